// Round 1
// baseline (1018.009 us; speedup 1.0000x reference)
//
#include <hip/hip_runtime.h>
#include <math.h>

// Problem constants
// B=8, T=16, IMG=128, CF=32, WO=HO=32, N=1024, M=32, DH=256
// conv SAME stride2: pad_lo=0, pad_hi=1  ->  in_idx = 2*out + k

#define TWOPI_32 0.19634954084936207f  // 2*pi/32

// ---------------- conv1: [img][3][128][128] -> [img][32][64][64], stride2 SAME, ReLU
__global__ __launch_bounds__(256) void conv1_kernel(const float* __restrict__ in,
                                                    const float* __restrict__ w,
                                                    const float* __restrict__ bias,
                                                    float* __restrict__ out)
{
    const int strip = blockIdx.x;   // 4 strips of 16 output rows
    const int img   = blockIdx.y;   // 128 images
    const int tid   = threadIdx.x;
    __shared__ float sIn[3*33*130];
    const int iy0 = strip * 32;
    for (int idx = tid; idx < 3*33*130; idx += 256) {
        int ic  = idx / (33*130);
        int rem = idx - ic*(33*130);
        int li  = rem / 130;
        int col = rem - li*130;
        int iy  = iy0 + li;
        float v = 0.f;
        if (iy < 128 && col < 128)
            v = in[(((size_t)img*3 + ic)*128 + iy)*128 + col];
        sIn[idx] = v;
    }
    __syncthreads();
    const int oy0 = strip*16;
    #pragma unroll
    for (int p = 0; p < 4; ++p) {
        int pos = p*256 + tid;       // 1024 positions: 16 rows x 64 cols
        int ly = pos >> 6;
        int ox = pos & 63;
        float r[27];
        #pragma unroll
        for (int ic = 0; ic < 3; ++ic)
            #pragma unroll
            for (int dy = 0; dy < 3; ++dy)
                #pragma unroll
                for (int dx = 0; dx < 3; ++dx)
                    r[(ic*3+dy)*3+dx] = sIn[ic*(33*130) + (2*ly+dy)*130 + 2*ox + dx];
        for (int oc = 0; oc < 32; ++oc) {
            float acc = bias[oc];
            #pragma unroll
            for (int q = 0; q < 27; ++q)
                acc += r[q] * w[oc*27 + q];
            out[(((size_t)img*32 + oc)*64 + (oy0+ly))*64 + ox] = fmaxf(acc, 0.f);
        }
    }
}

// ---------------- conv2: [img][32][64][64] -> [img][32][32][32], stride2 SAME, ReLU
__global__ __launch_bounds__(256) void conv2_kernel(const float* __restrict__ in,
                                                    const float* __restrict__ w,
                                                    const float* __restrict__ bias,
                                                    float* __restrict__ out)
{
    const int strip = blockIdx.x;   // 8 strips of 4 output rows
    const int img   = blockIdx.y;
    const int tid   = threadIdx.x;
    __shared__ float sIn[32*9*66];
    const int iy0 = strip*8;
    for (int idx = tid; idx < 32*9*66; idx += 256) {
        int ic  = idx / (9*66);
        int rem = idx - ic*(9*66);
        int li  = rem / 66;
        int col = rem - li*66;
        int iy  = iy0 + li;
        float v = 0.f;
        if (iy < 64 && col < 64)
            v = in[(((size_t)img*32 + ic)*64 + iy)*64 + col];
        sIn[idx] = v;
    }
    __syncthreads();
    const int posl = tid & 127;     // 128 positions: 4 rows x 32 cols
    const int half = tid >> 7;      // 2 halves of 16 out-channels
    const int ly = posl >> 5;
    const int ox = posl & 31;
    float acc[16];
    #pragma unroll
    for (int j = 0; j < 16; ++j) acc[j] = 0.f;
    for (int ic = 0; ic < 32; ++ic) {
        float r[9];
        #pragma unroll
        for (int dy = 0; dy < 3; ++dy)
            #pragma unroll
            for (int dx = 0; dx < 3; ++dx)
                r[dy*3+dx] = sIn[ic*(9*66) + (2*ly+dy)*66 + 2*ox + dx];
        #pragma unroll
        for (int j = 0; j < 16; ++j) {
            int oc = half*16 + j;
            const float* wp = &w[(oc*32 + ic)*9];
            float a = acc[j];
            #pragma unroll
            for (int q = 0; q < 9; ++q) a += r[q]*wp[q];
            acc[j] = a;
        }
    }
    const int oy = strip*4 + ly;
    #pragma unroll
    for (int j = 0; j < 16; ++j) {
        int oc = half*16 + j;
        out[(((size_t)img*32 + oc)*32 + oy)*32 + ox] = fmaxf(acc[j] + bias[oc], 0.f);
    }
}

// ---------------- NTM recurrence: one block per batch, 1024 threads (thread = slot n)
__device__ __forceinline__ float warpRed32(float s) {
    s += __shfl_down(s, 16, 32);
    s += __shfl_down(s, 8, 32);
    s += __shfl_down(s, 4, 32);
    s += __shfl_down(s, 2, 32);
    s += __shfl_down(s, 1, 32);
    return s;
}

__global__ __launch_bounds__(1024) void ntm_kernel(const float* __restrict__ xfeat,
    const float* __restrict__ Wk, const float* __restrict__ bk,
    const float* __restrict__ Wbeta, const float* __restrict__ bbeta,
    const float* __restrict__ Wh, const float* __restrict__ bh,
    const float* __restrict__ We, const float* __restrict__ Wa,
    const float* __restrict__ Wg, float* __restrict__ cseq)
{
    const int b    = blockIdx.x;
    const int tid  = threadIdx.x;
    const int lane = tid & 63;
    const int wid  = tid >> 6;
    const int n    = tid;

    __shared__ float sC[32][1024];   // memory matrix, m-major (conflict-free)
    __shared__ float sH[256];
    __shared__ float sInp[320];
    __shared__ float sK[32];
    __shared__ float sE[32];
    __shared__ float sA[32];
    __shared__ float sW[1024];
    __shared__ float sXm[32];
    __shared__ float sRed[34];
    __shared__ float sScal[4];

    // preload Wh slice into registers: row i = tid>>2, col-quarter q = tid&3
    float wreg[80];
    {
        const int wi = tid >> 2, wq = tid & 3;
        const float* wp = Wh + wi*320 + wq*80;
        #pragma unroll
        for (int jj = 0; jj < 80; ++jj) wreg[jj] = wp[jj];
    }
    if (tid < 256) sH[tid] = 0.f;

    // ---- init c = layernorm(x0) over (N,M)
    const float* x0 = xfeat + (size_t)(b*16)*32768;
    {
        float sum = 0.f, ss = 0.f;
        #pragma unroll
        for (int m = 0; m < 32; ++m) {
            float v = x0[m*1024 + n];
            sC[m][n] = v;
            sum += v; ss += v*v;
        }
        #pragma unroll
        for (int d = 32; d > 0; d >>= 1) { sum += __shfl_down(sum, d, 64); ss += __shfl_down(ss, d, 64); }
        if (lane == 0) { sRed[wid] = sum; sRed[16+wid] = ss; }
        __syncthreads();
        if (tid == 0) {
            float S = 0.f, SS = 0.f;
            for (int i = 0; i < 16; ++i) { S += sRed[i]; SS += sRed[16+i]; }
            float mu = S * (1.f/32768.f);
            float var = SS * (1.f/32768.f) - mu*mu;
            sScal[0] = mu;
            sScal[1] = rsqrtf(var + 1e-5f);
        }
        __syncthreads();
        float mu = sScal[0], rs = sScal[1];
        #pragma unroll
        for (int m = 0; m < 32; ++m) sC[m][n] = (sC[m][n] - mu) * rs;
    }
    __syncthreads();

    for (int t = 0; t < 16; ++t) {
        const float* xt = xfeat + (size_t)(b*16 + t)*32768;
        // ---- A: k = tanh(Wk h + bk) partials, and xmean; threads (m=tid>>5, j=tid&31)
        {
            const int m = tid >> 5, j = tid & 31;
            float s = 0.f;
            #pragma unroll
            for (int jj = 0; jj < 8; ++jj) s += Wk[m*256 + j + 32*jj] * sH[j + 32*jj];
            s = warpRed32(s);
            float xs = 0.f;
            #pragma unroll
            for (int jj = 0; jj < 32; ++jj) xs += xt[m*1024 + j + 32*jj];
            xs = warpRed32(xs);
            if (j == 0) { sK[m] = tanhf(s + bk[m]); sXm[m] = xs * (1.f/1024.f); }
        }
        __syncthreads();
        // ---- B0: beta (wave0), 1/(||k||+eps) (wave1), copy h->inp (waves 2..5)
        if (wid == 0) {
            float s = 0.f;
            #pragma unroll
            for (int jj = 0; jj < 4; ++jj) s += Wbeta[lane*4+jj] * sH[lane*4+jj];
            #pragma unroll
            for (int d = 32; d > 0; d >>= 1) s += __shfl_down(s, d, 64);
            if (lane == 0) {
                float x = s + bbeta[0];
                sScal[0] = (x > 20.f) ? x : log1pf(expf(x));   // softplus
            }
        } else if (wid == 1) {
            float v = (lane < 32) ? sK[lane] : 0.f;
            v = v*v;
            #pragma unroll
            for (int d = 32; d > 0; d >>= 1) v += __shfl_down(v, d, 64);
            if (lane == 0) sScal[1] = 1.f / (sqrtf(v) + 1e-8f);
        } else if (wid >= 2 && wid < 6) {
            int i = tid - 128;
            sInp[i] = sH[i];
        }
        __syncthreads();
        // ---- B: cosine sims + softmax weights
        float wn;
        {
            float beta = sScal[0], kinv = sScal[1];
            float cn2 = 0.f, dot = 0.f;
            #pragma unroll
            for (int m = 0; m < 32; ++m) {
                float c = sC[m][n];
                cn2 += c*c;
                dot += c * sK[m];
            }
            float sims = (dot * kinv) / (sqrtf(cn2) + 1e-8f);
            float sc = beta * sims;
            float mx = sc;
            #pragma unroll
            for (int d = 32; d > 0; d >>= 1) mx = fmaxf(mx, __shfl_down(mx, d, 64));
            if (lane == 0) sRed[wid] = mx;
            __syncthreads();
            if (tid == 0) { float g = sRed[0]; for (int i = 1; i < 16; ++i) g = fmaxf(g, sRed[i]); sRed[32] = g; }
            __syncthreads();
            float ex = expf(sc - sRed[32]);
            float s = ex;
            #pragma unroll
            for (int d = 32; d > 0; d >>= 1) s += __shfl_down(s, d, 64);
            if (lane == 0) sRed[wid] = s;
            __syncthreads();
            if (tid == 0) { float g = 0.f; for (int i = 0; i < 16; ++i) g += sRed[i]; sRed[33] = g; }
            __syncthreads();
            wn = ex / sRed[33];
            sW[n] = wn;
        }
        __syncthreads();
        // ---- C: r[m] = sum_n w_n c[n][m] -> inp[256+m]; xmean -> inp[288+m]
        {
            const int m = tid >> 5, j = tid & 31;
            float s = 0.f;
            #pragma unroll
            for (int jj = 0; jj < 32; ++jj) {
                int nn = j + 32*jj;
                s += sW[nn] * sC[m][nn];
            }
            s = warpRed32(s);
            if (j == 0) { sInp[256+m] = s; sInp[288+m] = sXm[m]; }
        }
        __syncthreads();
        // ---- D: h_new = tanh(Wh inp + bh); threads (i=tid>>2, q=tid&3)
        {
            const int i = tid >> 2, q = tid & 3;
            const float* ip = &sInp[q*80];
            float s = 0.f;
            #pragma unroll
            for (int jj = 0; jj < 80; ++jj) s += wreg[jj] * ip[jj];
            s += __shfl_down(s, 2, 4);
            s += __shfl_down(s, 1, 4);
            if (q == 0) sH[i] = tanhf(s + bh[i]);
        }
        __syncthreads();
        // ---- E: e = sig(We h), a = tanh(Wa h), g = sig(Wg h)
        if (tid < 256) {
            const int m = tid >> 3, j8 = tid & 7;
            float s = 0.f;
            #pragma unroll
            for (int jj = 0; jj < 32; ++jj) s += We[m*256 + j8 + 8*jj] * sH[j8 + 8*jj];
            s += __shfl_down(s, 4, 8); s += __shfl_down(s, 2, 8); s += __shfl_down(s, 1, 8);
            if (j8 == 0) sE[m] = 1.f/(1.f + expf(-s));
        } else if (tid < 512) {
            const int m = (tid-256) >> 3, j8 = tid & 7;
            float s = 0.f;
            #pragma unroll
            for (int jj = 0; jj < 32; ++jj) s += Wa[m*256 + j8 + 8*jj] * sH[j8 + 8*jj];
            s += __shfl_down(s, 4, 8); s += __shfl_down(s, 2, 8); s += __shfl_down(s, 1, 8);
            if (j8 == 0) sA[m] = tanhf(s);
        } else if (tid < 576) {
            const int l = tid - 512;
            float s = 0.f;
            #pragma unroll
            for (int jj = 0; jj < 4; ++jj) s += Wg[l*4+jj] * sH[l*4+jj];
            #pragma unroll
            for (int d = 32; d > 0; d >>= 1) s += __shfl_down(s, d, 64);
            if (l == 0) sScal[2] = 1.f/(1.f + expf(-s));
        }
        __syncthreads();
        // ---- F: erase/add/input-gate write; emit c_t in [BT][M][N] layout
        {
            float g = sScal[2];
            float* co = cseq + (size_t)(b*16+t)*32768;
            #pragma unroll
            for (int m = 0; m < 32; ++m) {
                float c   = sC[m][n];
                float cw2 = c * (1.f - wn * sE[m]) + wn * sA[m];
                float xv  = xt[m*1024 + n];
                float cnew = (1.f - g)*cw2 + g*xv;
                sC[m][n] = cnew;
                co[m*1024 + n] = cnew;
            }
        }
        __syncthreads();
    }
}

// ---------------- rfft2 of 32x32 windowed tile via 2-stage DFT; one block per (bt,m) image
__global__ __launch_bounds__(256) void fft_fwd_kernel(const float* __restrict__ src,
                                                      const float* __restrict__ cosw,
                                                      float* __restrict__ dst)
{
    const int img = blockIdx.x;
    const int tid = threadIdx.x;
    __shared__ float sY[1024];
    __shared__ float sR[32*17*2];
    __shared__ float ct[32], st[32];
    if (tid < 32) {
        float sv, cv;
        sincosf(TWOPI_32 * (float)tid, &sv, &cv);
        ct[tid] = cv; st[tid] = sv;
    }
    {
        float4 v = *(const float4*)&src[(size_t)img*1024 + tid*4];
        float4 c = *(const float4*)&cosw[tid*4];
        float4 o; o.x = v.x*c.x; o.y = v.y*c.y; o.z = v.z*c.z; o.w = v.w*c.w;
        *(float4*)&sY[tid*4] = o;
    }
    __syncthreads();
    // stage 1: rfft along w (last axis): R[h][k] = sum_w y e^{-2pi i w k/32}
    for (int idx = tid; idx < 544; idx += 256) {
        int h = idx / 17;
        int k = idx - h*17;
        const float* y = &sY[h*32];
        float re = 0.f, im = 0.f;
        #pragma unroll
        for (int wq = 0; wq < 32; ++wq) {
            int a = (wq*k) & 31;
            re += y[wq] * ct[a];
            im -= y[wq] * st[a];
        }
        sR[idx*2] = re; sR[idx*2+1] = im;
    }
    __syncthreads();
    // stage 2: full fft along h: F[j][k] = sum_h R[h][k] e^{-2pi i h j/32}
    for (int idx = tid; idx < 544; idx += 256) {
        int j = idx / 17;
        int k = idx - j*17;
        float re = 0.f, im = 0.f;
        #pragma unroll
        for (int h = 0; h < 32; ++h) {
            float ar = sR[(h*17+k)*2], ai = sR[(h*17+k)*2+1];
            int a = (h*j) & 31;
            float c = ct[a], s = st[a];
            re += ar*c + ai*s;
            im += ai*c - ar*s;
        }
        dst[((size_t)img*544 + idx)*2]     = re;
        dst[((size_t)img*544 + idx)*2 + 1] = im;
    }
}

// ---------------- channel-sum DCF combine: rf = (sum_m z*conj(c)) * yf/(sum_m |c|^2 + lambda)
__global__ __launch_bounds__(256) void combine_kernel(const float* __restrict__ cfft,
                                                      const float* __restrict__ zfft,
                                                      const float* __restrict__ yf,
                                                      float* __restrict__ rfreq)
{
    const int bt  = blockIdx.x;
    const int tid = threadIdx.x;
    for (int idx = tid; idx < 544; idx += 256) {
        float kzz = 0.f, kxr = 0.f, kxi = 0.f;
        for (int m = 0; m < 32; ++m) {
            size_t base = ((size_t)(bt*32 + m)*544 + idx)*2;
            float cr = cfft[base], ci = cfft[base+1];
            float zr = zfft[base], zi = zfft[base+1];
            kzz += cr*cr + ci*ci;
            kxr += zr*cr + zi*ci;   // z * conj(c)
            kxi += zi*cr - zr*ci;
        }
        float den = 1.f / (kzz + 1e-4f);
        float ar = yf[idx*2] * den, ai = yf[idx*2+1] * den;
        rfreq[((size_t)bt*544 + idx)*2]     = kxr*ar - kxi*ai;
        rfreq[((size_t)bt*544 + idx)*2 + 1] = kxr*ai + kxi*ar;
    }
}

// ---------------- irfft2 back to 32x32 real response; one block per bt
__global__ __launch_bounds__(256) void ifft_kernel(const float* __restrict__ rfreq,
                                                   float* __restrict__ out)
{
    const int bt  = blockIdx.x;
    const int tid = threadIdx.x;
    __shared__ float sG[544*2];
    __shared__ float sS[544*2];
    __shared__ float ct[32], st[32];
    if (tid < 32) {
        float sv, cv;
        sincosf(TWOPI_32 * (float)tid, &sv, &cv);
        ct[tid] = cv; st[tid] = sv;
    }
    for (int i = tid; i < 1088; i += 256) sG[i] = rfreq[(size_t)bt*1088 + i];
    __syncthreads();
    // stage 1: inverse fft along j: S[h][k] = sum_j G[j][k] e^{+2pi i h j/32}
    for (int idx = tid; idx < 544; idx += 256) {
        int h = idx / 17;
        int k = idx - h*17;
        float re = 0.f, im = 0.f;
        #pragma unroll
        for (int j = 0; j < 32; ++j) {
            float gr = sG[(j*17+k)*2], gi = sG[(j*17+k)*2+1];
            int a = (h*j) & 31;
            float c = ct[a], s = st[a];
            re += gr*c - gi*s;
            im += gr*s + gi*c;
        }
        sS[(h*17+k)*2] = re; sS[(h*17+k)*2+1] = im;
    }
    __syncthreads();
    // stage 2: inverse rfft along w with hermitian extension; scale 1/(32*32)
    #pragma unroll
    for (int p = 0; p < 4; ++p) {
        int pos = p*256 + tid;
        int h = pos >> 5, wq = pos & 31;
        float acc = sS[(h*17)*2];
        #pragma unroll
        for (int k = 1; k < 16; ++k) {
            int a = (wq*k) & 31;
            acc += 2.f*(sS[(h*17+k)*2]*ct[a] - sS[(h*17+k)*2+1]*st[a]);
        }
        acc += sS[(h*17+16)*2] * ((wq & 1) ? -1.f : 1.f);
        out[(size_t)bt*1024 + pos] = acc * (1.f/1024.f);
    }
}

extern "C" void kernel_launch(void* const* d_in, const int* in_sizes, int n_in,
                              void* d_out, int out_size, void* d_ws, size_t ws_size,
                              hipStream_t stream)
{
    const float* x_i   = (const float*)d_in[0];
    const float* z_i   = (const float*)d_in[1];
    const float* c1w   = (const float*)d_in[2];
    const float* c1b   = (const float*)d_in[3];
    const float* c2w   = (const float*)d_in[4];
    const float* c2b   = (const float*)d_in[5];
    const float* Wk    = (const float*)d_in[6];
    const float* bk    = (const float*)d_in[7];
    const float* Wbeta = (const float*)d_in[8];
    const float* bbeta = (const float*)d_in[9];
    const float* Wh    = (const float*)d_in[10];
    const float* bh    = (const float*)d_in[11];
    const float* We    = (const float*)d_in[12];
    const float* Wa    = (const float*)d_in[13];
    const float* Wg    = (const float*)d_in[14];
    const float* cosw  = (const float*)d_in[15];
    const float* yf    = (const float*)d_in[16];
    float* out = (float*)d_out;
    float* ws  = (float*)d_ws;

    // workspace layout (floats); peak use ~118 MB
    float* buf1  = ws;                 // conv1 out, 128*32*64*64 = 16,777,216
    float* xfeat = ws + 16777216;      // 128*32*32*32 = 4,194,304
    float* zfeat = ws + 20971520;      // 4,194,304
    float* cseq  = ws + 25165824;      // NTM memory sequence [BT][M][N] = 4,194,304
    float* rfreq = ws + 29360128;      // 128*544*2 = 139,264
    float* cfft  = buf1;               // alias conv1 buffer (free after conv2(z))
    float* zfft  = buf1 + 4456448;     // 4,456,448 each

    dim3 b256(256);
    conv1_kernel<<<dim3(4,128), b256, 0, stream>>>(x_i, c1w, c1b, buf1);
    conv2_kernel<<<dim3(8,128), b256, 0, stream>>>(buf1, c2w, c2b, xfeat);
    conv1_kernel<<<dim3(4,128), b256, 0, stream>>>(z_i, c1w, c1b, buf1);
    conv2_kernel<<<dim3(8,128), b256, 0, stream>>>(buf1, c2w, c2b, zfeat);
    ntm_kernel<<<8, 1024, 0, stream>>>(xfeat, Wk, bk, Wbeta, bbeta, Wh, bh, We, Wa, Wg, cseq);
    fft_fwd_kernel<<<4096, b256, 0, stream>>>(cseq, cosw, cfft);
    fft_fwd_kernel<<<4096, b256, 0, stream>>>(zfeat, cosw, zfft);
    combine_kernel<<<128, b256, 0, stream>>>(cfft, zfft, yf, rfreq);
    ifft_kernel<<<128, b256, 0, stream>>>(rfreq, out);
}

// Round 2
// 979.711 us; speedup vs baseline: 1.0391x; 1.0391x over previous
//
#include <hip/hip_runtime.h>
#include <hip/hip_fp16.h>
#include <math.h>

// Problem constants
// B=8, T=16, IMG=128, CF=32, WO=HO=32, N=1024, M=32, DH=256
// conv SAME stride2: pad_lo=0, pad_hi=1  ->  in_idx = 2*out + k

#define TWOPI_32 0.19634954084936207f  // 2*pi/32

// ---------------- conv1: [img][3][128][128] -> [img][32][64][64], stride2 SAME, ReLU
__global__ __launch_bounds__(256) void conv1_kernel(const float* __restrict__ in,
                                                    const float* __restrict__ w,
                                                    const float* __restrict__ bias,
                                                    float* __restrict__ out)
{
    const int strip = blockIdx.x;   // 4 strips of 16 output rows
    const int img   = blockIdx.y;   // 128 images
    const int tid   = threadIdx.x;
    __shared__ float sIn[3*33*130];
    const int iy0 = strip * 32;
    for (int idx = tid; idx < 3*33*130; idx += 256) {
        int ic  = idx / (33*130);
        int rem = idx - ic*(33*130);
        int li  = rem / 130;
        int col = rem - li*130;
        int iy  = iy0 + li;
        float v = 0.f;
        if (iy < 128 && col < 128)
            v = in[(((size_t)img*3 + ic)*128 + iy)*128 + col];
        sIn[idx] = v;
    }
    __syncthreads();
    const int oy0 = strip*16;
    #pragma unroll
    for (int p = 0; p < 4; ++p) {
        int pos = p*256 + tid;       // 1024 positions: 16 rows x 64 cols
        int ly = pos >> 6;
        int ox = pos & 63;
        float r[27];
        #pragma unroll
        for (int ic = 0; ic < 3; ++ic)
            #pragma unroll
            for (int dy = 0; dy < 3; ++dy)
                #pragma unroll
                for (int dx = 0; dx < 3; ++dx)
                    r[(ic*3+dy)*3+dx] = sIn[ic*(33*130) + (2*ly+dy)*130 + 2*ox + dx];
        for (int oc = 0; oc < 32; ++oc) {
            float acc = bias[oc];
            #pragma unroll
            for (int q = 0; q < 27; ++q)
                acc += r[q] * w[oc*27 + q];
            out[(((size_t)img*32 + oc)*64 + (oy0+ly))*64 + ox] = fmaxf(acc, 0.f);
        }
    }
}

// ---------------- conv2: [img][32][64][64] -> [img][32][32][32], stride2 SAME, ReLU
__global__ __launch_bounds__(256) void conv2_kernel(const float* __restrict__ in,
                                                    const float* __restrict__ w,
                                                    const float* __restrict__ bias,
                                                    float* __restrict__ out)
{
    const int strip = blockIdx.x;   // 8 strips of 4 output rows
    const int img   = blockIdx.y;
    const int tid   = threadIdx.x;
    __shared__ float sIn[32*9*66];
    const int iy0 = strip*8;
    for (int idx = tid; idx < 32*9*66; idx += 256) {
        int ic  = idx / (9*66);
        int rem = idx - ic*(9*66);
        int li  = rem / 66;
        int col = rem - li*66;
        int iy  = iy0 + li;
        float v = 0.f;
        if (iy < 64 && col < 64)
            v = in[(((size_t)img*32 + ic)*64 + iy)*64 + col];
        sIn[idx] = v;
    }
    __syncthreads();
    const int posl = tid & 127;     // 128 positions: 4 rows x 32 cols
    const int half = tid >> 7;      // 2 halves of 16 out-channels
    const int ly = posl >> 5;
    const int ox = posl & 31;
    float acc[16];
    #pragma unroll
    for (int j = 0; j < 16; ++j) acc[j] = 0.f;
    for (int ic = 0; ic < 32; ++ic) {
        float r[9];
        #pragma unroll
        for (int dy = 0; dy < 3; ++dy)
            #pragma unroll
            for (int dx = 0; dx < 3; ++dx)
                r[dy*3+dx] = sIn[ic*(9*66) + (2*ly+dy)*66 + 2*ox + dx];
        #pragma unroll
        for (int j = 0; j < 16; ++j) {
            int oc = half*16 + j;
            const float* wp = &w[(oc*32 + ic)*9];
            float a = acc[j];
            #pragma unroll
            for (int q = 0; q < 9; ++q) a += r[q]*wp[q];
            acc[j] = a;
        }
    }
    const int oy = strip*4 + ly;
    #pragma unroll
    for (int j = 0; j < 16; ++j) {
        int oc = half*16 + j;
        out[(((size_t)img*32 + oc)*32 + oy)*32 + ox] = fmaxf(acc[j] + bias[oc], 0.f);
    }
}

// ---------------- xmean: mean over n of xfeat rows [(bt*32+m)][1024]
__global__ __launch_bounds__(256) void xmean_kernel(const float* __restrict__ xfeat,
                                                    float* __restrict__ xmean)
{
    const int row  = blockIdx.x*4 + (threadIdx.x >> 6);   // 4096 rows
    const int lane = threadIdx.x & 63;
    const float* p = xfeat + (size_t)row*1024;
    float s = 0.f;
    #pragma unroll
    for (int jj = 0; jj < 16; ++jj) s += p[lane + 64*jj];
    #pragma unroll
    for (int d = 32; d > 0; d >>= 1) s += __shfl_xor(s, d, 64);
    if (lane == 0) xmean[row] = s * (1.f/1024.f);
}

// ---------------- NTM recurrence: one block per batch, 512 threads (thread owns cols 2t,2t+1)
__global__ __launch_bounds__(512, 2) void ntm_kernel(
    const float* __restrict__ xfeat, const float* __restrict__ xmean,
    const float* __restrict__ Wk, const float* __restrict__ bk,
    const float* __restrict__ Wbeta, const float* __restrict__ bbeta,
    const float* __restrict__ Wh, const float* __restrict__ bh,
    const float* __restrict__ We, const float* __restrict__ Wa,
    const float* __restrict__ Wg, float* __restrict__ cseq)
{
    const int b    = blockIdx.x;
    const int tid  = threadIdx.x;
    const int lane = tid & 63;
    const int wid  = tid >> 6;

    // n-major swizzled c mirror: row n (32 floats), chunk q at float-off n*32 + ((q ^ ((n>>1)&7))<<2)
    __shared__ __align__(16) float sC[32768];
    __shared__ __align__(16) float sK[32];
    __shared__ __align__(16) float sInp[320];
    __shared__ __align__(16) float sE[32];
    __shared__ __align__(16) float sA[32];
    __shared__ float sW[1024];
    __shared__ float sH[256];
    __shared__ float sBh[256];
    __shared__ float sBk[32];
    __shared__ float sRedD[8];
    __shared__ float sRedB[4];
    __shared__ float sRedG[4];
    __shared__ float sRedL[16];

    // ---- weight registers (no spill: ~198 persistent VGPRs)
    unsigned int wh[80];                  // Wh[i][q*160..+159] as f16x2; (i=tid>>1, q=tid&1)
    {
        const int i = tid >> 1, q = tid & 1;
        const float* wp = Wh + i*320 + q*160;
        #pragma unroll
        for (int jj = 0; jj < 80; ++jj) {
            float2 v = *(const float2*)&wp[2*jj];
            __half2 h2 = __floats2half2_rn(v.x, v.y);
            wh[jj] = *(unsigned int*)&h2;
        }
    }
    float wk[16], we[16], wa[16];         // W[m][j+16jj]; (m=tid>>4, j=tid&15)
    {
        const int m = tid >> 4, j = tid & 15;
        #pragma unroll
        for (int jj = 0; jj < 16; ++jj) {
            wk[jj] = Wk[m*256 + j + 16*jj];
            we[jj] = We[m*256 + j + 16*jj];
            wa[jj] = Wa[m*256 + j + 16*jj];
        }
    }
    float wb = (tid < 256) ? Wbeta[tid] : 0.f;
    float wg = (tid < 256) ? Wg[tid] : 0.f;
    float bb = bbeta[0];
    if (tid < 256) { sBh[tid] = bh[tid]; sH[tid] = 0.f; }
    if (tid < 32)  sBk[tid] = bk[tid];

    const int n0 = 2*tid, n1 = 2*tid + 1;
    const int sw = tid & 7;               // = (n0>>1)&7 = (n1>>1)&7
    float c0[32], c1[32];

    // ---- init: c = layernorm(x0) over (N,M)
    {
        const float* x0 = xfeat + (size_t)(b*16)*32768;
        float sum = 0.f, ss = 0.f;
        #pragma unroll
        for (int m = 0; m < 32; ++m) {
            float2 v = *(const float2*)&x0[m*1024 + n0];
            c0[m] = v.x; c1[m] = v.y;
            sum += v.x + v.y; ss += v.x*v.x + v.y*v.y;
        }
        #pragma unroll
        for (int d = 32; d > 0; d >>= 1) { sum += __shfl_xor(sum, d, 64); ss += __shfl_xor(ss, d, 64); }
        if (lane == 0) { sRedL[wid] = sum; sRedL[8+wid] = ss; }
        __syncthreads();
        float S = 0.f, SS = 0.f;
        #pragma unroll
        for (int i = 0; i < 8; ++i) { S += sRedL[i]; SS += sRedL[8+i]; }
        float mu = S * (1.f/32768.f);
        float var = SS * (1.f/32768.f) - mu*mu;
        float rs = rsqrtf(var + 1e-5f);
        #pragma unroll
        for (int m = 0; m < 32; ++m) { c0[m] = (c0[m]-mu)*rs; c1[m] = (c1[m]-mu)*rs; }
        #pragma unroll
        for (int q = 0; q < 8; ++q) {
            *(float4*)&sC[n0*32 + ((q ^ sw)<<2)] = make_float4(c0[4*q], c0[4*q+1], c0[4*q+2], c0[4*q+3]);
            *(float4*)&sC[n1*32 + ((q ^ sw)<<2)] = make_float4(c1[4*q], c1[4*q+1], c1[4*q+2], c1[4*q+3]);
        }
    }
    __syncthreads();

    float ex0 = 0.f, ex1 = 0.f;
    for (int t = 0; t < 16; ++t) {
        const float* xt = xfeat + (size_t)(b*16 + t)*32768;

        // ---- A: k = tanh(Wk h + bk); beta partials; stage inp = [h, ., xmean]
        {
            const int m = tid >> 4, j = tid & 15;
            float s = 0.f;
            #pragma unroll
            for (int jj = 0; jj < 16; ++jj) s += wk[jj] * sH[j + 16*jj];
            s += __shfl_down(s, 8, 16); s += __shfl_down(s, 4, 16);
            s += __shfl_down(s, 2, 16); s += __shfl_down(s, 1, 16);
            if (j == 0) sK[m] = tanhf(s + sBk[m]);
            float p = (tid < 256) ? wb * sH[tid] : 0.f;
            #pragma unroll
            for (int d = 32; d > 0; d >>= 1) p += __shfl_xor(p, d, 64);
            if (lane == 0 && wid < 4) sRedB[wid] = p;
            if (tid < 256) sInp[tid] = sH[tid];
            if (tid < 32)  sInp[288 + tid] = xmean[(b*16 + t)*32 + tid];
        }
        __syncthreads();

        // ---- B: cosine sims + exp (no max-sub needed: |beta*sims| <= ~13)
        {
            float x = sRedB[0] + sRedB[1] + sRedB[2] + sRedB[3] + bb;
            float beta = (x > 20.f) ? x : log1pf(expf(x));
            float dot0 = 0.f, dot1 = 0.f, cn20 = 0.f, cn21 = 0.f, kn2 = 0.f;
            #pragma unroll
            for (int q = 0; q < 8; ++q) {
                float4 k4 = *(const float4*)&sK[4*q];
                dot0 += c0[4*q]*k4.x + c0[4*q+1]*k4.y + c0[4*q+2]*k4.z + c0[4*q+3]*k4.w;
                dot1 += c1[4*q]*k4.x + c1[4*q+1]*k4.y + c1[4*q+2]*k4.z + c1[4*q+3]*k4.w;
                cn20 += c0[4*q]*c0[4*q] + c0[4*q+1]*c0[4*q+1] + c0[4*q+2]*c0[4*q+2] + c0[4*q+3]*c0[4*q+3];
                cn21 += c1[4*q]*c1[4*q] + c1[4*q+1]*c1[4*q+1] + c1[4*q+2]*c1[4*q+2] + c1[4*q+3]*c1[4*q+3];
                kn2  += k4.x*k4.x + k4.y*k4.y + k4.z*k4.z + k4.w*k4.w;
            }
            float kinv = 1.f / (sqrtf(kn2) + 1e-8f);
            float s0 = dot0 * kinv / (sqrtf(cn20) + 1e-8f);
            float s1 = dot1 * kinv / (sqrtf(cn21) + 1e-8f);
            ex0 = expf(beta * s0);
            ex1 = expf(beta * s1);
            *(float2*)&sW[n0] = make_float2(ex0, ex1);
            float es = ex0 + ex1;
            #pragma unroll
            for (int d = 32; d > 0; d >>= 1) es += __shfl_xor(es, d, 64);
            if (lane == 0) sRedD[wid] = es;
        }
        __syncthreads();

        // ---- C: r[m] = sum_n ex_n c[n][m] / denom; wave ch owns m-chunk ch
        {
            const int ch = wid, j = lane;
            float4 r = make_float4(0.f, 0.f, 0.f, 0.f);
            #pragma unroll
            for (int jj = 0; jj < 16; ++jj) {
                int n = j + 64*jj;
                float ex = sW[n];
                float4 cv = *(const float4*)&sC[n*32 + (((ch ^ ((n>>1)&7)))<<2)];
                r.x += ex*cv.x; r.y += ex*cv.y; r.z += ex*cv.z; r.w += ex*cv.w;
            }
            #pragma unroll
            for (int d = 32; d > 0; d >>= 1) {
                r.x += __shfl_xor(r.x, d, 64); r.y += __shfl_xor(r.y, d, 64);
                r.z += __shfl_xor(r.z, d, 64); r.w += __shfl_xor(r.w, d, 64);
            }
            if (j == 0) {
                float den = sRedD[0]+sRedD[1]+sRedD[2]+sRedD[3]+sRedD[4]+sRedD[5]+sRedD[6]+sRedD[7];
                float inv = 1.f / den;
                *(float4*)&sInp[256 + 4*ch] = make_float4(r.x*inv, r.y*inv, r.z*inv, r.w*inv);
            }
        }
        __syncthreads();

        // ---- D: h_new = tanh(Wh inp + bh); pair (i=tid>>1, q=tid&1)
        {
            const int i = tid >> 1, q = tid & 1;
            const float* ip = &sInp[q*160];
            float s = 0.f;
            #pragma unroll
            for (int jj = 0; jj < 40; ++jj) {
                float4 v = *(const float4*)&ip[4*jj];
                __half2 a2 = *(__half2*)&wh[2*jj];
                __half2 b2 = *(__half2*)&wh[2*jj+1];
                float2 fa = __half22float2(a2), fb = __half22float2(b2);
                s += fa.x*v.x + fa.y*v.y + fb.x*v.z + fb.y*v.w;
            }
            s += __shfl_down(s, 1, 2);
            if (q == 0) sH[i] = tanhf(s + sBh[i]);
        }
        __syncthreads();

        // ---- E: e = sig(We h), a = tanh(Wa h), g partials
        {
            const int m = tid >> 4, j = tid & 15;
            float se = 0.f, sa = 0.f;
            #pragma unroll
            for (int jj = 0; jj < 16; ++jj) {
                float hv = sH[j + 16*jj];
                se += we[jj]*hv; sa += wa[jj]*hv;
            }
            se += __shfl_down(se, 8, 16); sa += __shfl_down(sa, 8, 16);
            se += __shfl_down(se, 4, 16); sa += __shfl_down(sa, 4, 16);
            se += __shfl_down(se, 2, 16); sa += __shfl_down(sa, 2, 16);
            se += __shfl_down(se, 1, 16); sa += __shfl_down(sa, 1, 16);
            if (j == 0) { sE[m] = 1.f/(1.f + expf(-se)); sA[m] = tanhf(sa); }
            float p = (tid < 256) ? wg * sH[tid] : 0.f;
            #pragma unroll
            for (int d = 32; d > 0; d >>= 1) p += __shfl_xor(p, d, 64);
            if (lane == 0 && wid < 4) sRedG[wid] = p;
        }
        __syncthreads();

        // ---- F: erase/add/gate write; update regs + LDS mirror + global cseq
        {
            float gx = sRedG[0] + sRedG[1] + sRedG[2] + sRedG[3];
            float gg = 1.f / (1.f + expf(-gx));
            float den = sRedD[0]+sRedD[1]+sRedD[2]+sRedD[3]+sRedD[4]+sRedD[5]+sRedD[6]+sRedD[7];
            float inv = 1.f / den;
            float w0 = ex0 * inv, w1 = ex1 * inv;
            float omg = 1.f - gg;
            float* co = cseq + (size_t)(b*16 + t)*32768;
            #pragma unroll
            for (int half = 0; half < 2; ++half) {
                float2 xv[16];
                #pragma unroll
                for (int mm = 0; mm < 16; ++mm)
                    xv[mm] = *(const float2*)&xt[(half*16 + mm)*1024 + n0];
                #pragma unroll
                for (int qq = 0; qq < 4; ++qq) {
                    const int q = half*4 + qq;
                    float4 e4 = *(const float4*)&sE[4*q];
                    float4 a4 = *(const float4*)&sA[4*q];
                    float o0[4], o1[4];
                    #pragma unroll
                    for (int r = 0; r < 4; ++r) {
                        int m = 4*q + r;
                        float e = (r==0)?e4.x:(r==1)?e4.y:(r==2)?e4.z:e4.w;
                        float a = (r==0)?a4.x:(r==1)?a4.y:(r==2)?a4.z:a4.w;
                        float2 xvv = xv[m - half*16];
                        float cw0 = c0[m]*(1.f - w0*e) + w0*a;
                        float cw1 = c1[m]*(1.f - w1*e) + w1*a;
                        float cn0 = omg*cw0 + gg*xvv.x;
                        float cn1 = omg*cw1 + gg*xvv.y;
                        c0[m] = cn0; c1[m] = cn1;
                        o0[r] = cn0; o1[r] = cn1;
                        *(float2*)&co[m*1024 + n0] = make_float2(cn0, cn1);
                    }
                    *(float4*)&sC[n0*32 + ((q ^ sw)<<2)] = make_float4(o0[0], o0[1], o0[2], o0[3]);
                    *(float4*)&sC[n1*32 + ((q ^ sw)<<2)] = make_float4(o1[0], o1[1], o1[2], o1[3]);
                }
            }
        }
        __syncthreads();
    }
}

// ---------------- rfft2 of 32x32 windowed tile via 2-stage DFT; one block per (bt,m) image
__global__ __launch_bounds__(256) void fft_fwd_kernel(const float* __restrict__ src,
                                                      const float* __restrict__ cosw,
                                                      float* __restrict__ dst)
{
    const int img = blockIdx.x;
    const int tid = threadIdx.x;
    __shared__ float sY[1024];
    __shared__ float sR[32*17*2];
    __shared__ float ct[32], st[32];
    if (tid < 32) {
        float sv, cv;
        sincosf(TWOPI_32 * (float)tid, &sv, &cv);
        ct[tid] = cv; st[tid] = sv;
    }
    {
        float4 v = *(const float4*)&src[(size_t)img*1024 + tid*4];
        float4 c = *(const float4*)&cosw[tid*4];
        float4 o; o.x = v.x*c.x; o.y = v.y*c.y; o.z = v.z*c.z; o.w = v.w*c.w;
        *(float4*)&sY[tid*4] = o;
    }
    __syncthreads();
    // stage 1: rfft along w: R[h][k] = sum_w y e^{-2pi i w k/32}
    for (int idx = tid; idx < 544; idx += 256) {
        int h = idx / 17;
        int k = idx - h*17;
        const float* y = &sY[h*32];
        float re = 0.f, im = 0.f;
        #pragma unroll
        for (int wq = 0; wq < 32; ++wq) {
            int a = (wq*k) & 31;
            re += y[wq] * ct[a];
            im -= y[wq] * st[a];
        }
        sR[idx*2] = re; sR[idx*2+1] = im;
    }
    __syncthreads();
    // stage 2: full fft along h
    for (int idx = tid; idx < 544; idx += 256) {
        int j = idx / 17;
        int k = idx - j*17;
        float re = 0.f, im = 0.f;
        #pragma unroll
        for (int h = 0; h < 32; ++h) {
            float ar = sR[(h*17+k)*2], ai = sR[(h*17+k)*2+1];
            int a = (h*j) & 31;
            float c = ct[a], s = st[a];
            re += ar*c + ai*s;
            im += ai*c - ar*s;
        }
        dst[((size_t)img*544 + idx)*2]     = re;
        dst[((size_t)img*544 + idx)*2 + 1] = im;
    }
}

// ---------------- channel-sum DCF combine (parallel: 1 thread per (bt,idx))
__global__ __launch_bounds__(256) void combine_kernel(const float* __restrict__ cfft,
                                                      const float* __restrict__ zfft,
                                                      const float* __restrict__ yf,
                                                      float* __restrict__ rfreq)
{
    int gid = blockIdx.x*256 + threadIdx.x;
    if (gid >= 128*544) return;
    int bt  = gid / 544;
    int idx = gid - bt*544;
    float kzz = 0.f, kxr = 0.f, kxi = 0.f;
    #pragma unroll 4
    for (int m = 0; m < 32; ++m) {
        size_t base = ((size_t)(bt*32 + m)*544 + idx)*2;
        float2 c = *(const float2*)&cfft[base];
        float2 z = *(const float2*)&zfft[base];
        kzz += c.x*c.x + c.y*c.y;
        kxr += z.x*c.x + z.y*c.y;   // z * conj(c)
        kxi += z.y*c.x - z.x*c.y;
    }
    float den = 1.f / (kzz + 1e-4f);
    float2 y = *(const float2*)&yf[idx*2];
    float ar = y.x*den, ai = y.y*den;
    *(float2*)&rfreq[(size_t)gid*2] = make_float2(kxr*ar - kxi*ai, kxr*ai + kxi*ar);
}

// ---------------- irfft2 back to 32x32 real response; one block per bt
__global__ __launch_bounds__(256) void ifft_kernel(const float* __restrict__ rfreq,
                                                   float* __restrict__ out)
{
    const int bt  = blockIdx.x;
    const int tid = threadIdx.x;
    __shared__ float sG[544*2];
    __shared__ float sS[544*2];
    __shared__ float ct[32], st[32];
    if (tid < 32) {
        float sv, cv;
        sincosf(TWOPI_32 * (float)tid, &sv, &cv);
        ct[tid] = cv; st[tid] = sv;
    }
    for (int i = tid; i < 1088; i += 256) sG[i] = rfreq[(size_t)bt*1088 + i];
    __syncthreads();
    // stage 1: inverse fft along j
    for (int idx = tid; idx < 544; idx += 256) {
        int h = idx / 17;
        int k = idx - h*17;
        float re = 0.f, im = 0.f;
        #pragma unroll
        for (int j = 0; j < 32; ++j) {
            float gr = sG[(j*17+k)*2], gi = sG[(j*17+k)*2+1];
            int a = (h*j) & 31;
            float c = ct[a], s = st[a];
            re += gr*c - gi*s;
            im += gr*s + gi*c;
        }
        sS[(h*17+k)*2] = re; sS[(h*17+k)*2+1] = im;
    }
    __syncthreads();
    // stage 2: inverse rfft along w with hermitian extension; scale 1/1024
    #pragma unroll
    for (int p = 0; p < 4; ++p) {
        int pos = p*256 + tid;
        int h = pos >> 5, wq = pos & 31;
        float acc = sS[(h*17)*2];
        #pragma unroll
        for (int k = 1; k < 16; ++k) {
            int a = (wq*k) & 31;
            acc += 2.f*(sS[(h*17+k)*2]*ct[a] - sS[(h*17+k)*2+1]*st[a]);
        }
        acc += sS[(h*17+16)*2] * ((wq & 1) ? -1.f : 1.f);
        out[(size_t)bt*1024 + pos] = acc * (1.f/1024.f);
    }
}

extern "C" void kernel_launch(void* const* d_in, const int* in_sizes, int n_in,
                              void* d_out, int out_size, void* d_ws, size_t ws_size,
                              hipStream_t stream)
{
    const float* x_i   = (const float*)d_in[0];
    const float* z_i   = (const float*)d_in[1];
    const float* c1w   = (const float*)d_in[2];
    const float* c1b   = (const float*)d_in[3];
    const float* c2w   = (const float*)d_in[4];
    const float* c2b   = (const float*)d_in[5];
    const float* Wk    = (const float*)d_in[6];
    const float* bk    = (const float*)d_in[7];
    const float* Wbeta = (const float*)d_in[8];
    const float* bbeta = (const float*)d_in[9];
    const float* Wh    = (const float*)d_in[10];
    const float* bh    = (const float*)d_in[11];
    const float* We    = (const float*)d_in[12];
    const float* Wa    = (const float*)d_in[13];
    const float* Wg    = (const float*)d_in[14];
    const float* cosw  = (const float*)d_in[15];
    const float* yf    = (const float*)d_in[16];
    float* out = (float*)d_out;
    float* ws  = (float*)d_ws;

    // workspace layout (floats); peak use ~118 MB
    float* buf1  = ws;                 // conv1 out, 16,777,216
    float* xfeat = ws + 16777216;      // 4,194,304
    float* zfeat = ws + 20971520;      // 4,194,304
    float* cseq  = ws + 25165824;      // 4,194,304
    float* rfreq = ws + 29360128;      // 139,264
    float* xmb   = ws + 29499392;      // 4,096
    float* cfft  = buf1;               // alias conv1 buffer (free after conv2(z))
    float* zfft  = buf1 + 4456448;

    dim3 b256(256);
    conv1_kernel<<<dim3(4,128), b256, 0, stream>>>(x_i, c1w, c1b, buf1);
    conv2_kernel<<<dim3(8,128), b256, 0, stream>>>(buf1, c2w, c2b, xfeat);
    conv1_kernel<<<dim3(4,128), b256, 0, stream>>>(z_i, c1w, c1b, buf1);
    conv2_kernel<<<dim3(8,128), b256, 0, stream>>>(buf1, c2w, c2b, zfeat);
    xmean_kernel<<<1024, b256, 0, stream>>>(xfeat, xmb);
    ntm_kernel<<<8, 512, 0, stream>>>(xfeat, xmb, Wk, bk, Wbeta, bbeta, Wh, bh, We, Wa, Wg, cseq);
    fft_fwd_kernel<<<4096, b256, 0, stream>>>(cseq, cosw, cfft);
    fft_fwd_kernel<<<4096, b256, 0, stream>>>(zfeat, cosw, zfft);
    combine_kernel<<<272, b256, 0, stream>>>(cfft, zfft, yf, rfreq);
    ifft_kernel<<<128, b256, 0, stream>>>(rfreq, out);
}